// Round 11
// baseline (308.255 us; speedup 1.0000x reference)
//
#include <hip/hip_runtime.h>
#include <hip/hip_bf16.h>

// ---------- helpers ----------
typedef __bf16 bf16x8 __attribute__((ext_vector_type(8)));
typedef float f32x4 __attribute__((ext_vector_type(4)));
typedef unsigned short u16x8 __attribute__((ext_vector_type(8)));

__device__ __forceinline__ unsigned short f2bf(float f) {
  unsigned u = __float_as_uint(f);
  u += 0x7FFF + ((u >> 16) & 1);          // RNE
  return (unsigned short)(u >> 16);
}
__device__ __forceinline__ float bf2f(unsigned short h) {
  return __uint_as_float((unsigned)h << 16);
}

__device__ __forceinline__ void gload_lds16(const void* g, void* l) {
  __builtin_amdgcn_global_load_lds(
      (const __attribute__((address_space(1))) void*)g,
      (__attribute__((address_space(3))) void*)l, 16, 0, 0);
}

// ---------- 1) row softmax of 4 P matrices -> bf16 ----------
__global__ __launch_bounds__(256)
void softmax4_kernel(const float* __restrict__ P0, const float* __restrict__ P1,
                     const float* __restrict__ P2, const float* __restrict__ P3,
                     unsigned short* __restrict__ S)
{
  const int bid = blockIdx.x;
  const int mat = bid >> 10, row = bid & 1023;
  const float* P = (mat == 0 ? P0 : mat == 1 ? P1 : mat == 2 ? P2 : P3) + (size_t)row * 1024;
  unsigned short* out = S + ((size_t)mat << 20) + (size_t)row * 1024;
  const int t = threadIdx.x, w = t >> 6, l = t & 63;
  float4 v = ((const float4*)P)[t];
  float mx = fmaxf(fmaxf(v.x, v.y), fmaxf(v.z, v.w));
  #pragma unroll
  for (int off = 32; off > 0; off >>= 1) mx = fmaxf(mx, __shfl_xor(mx, off));
  __shared__ float redA[4], redB[4];
  if (l == 0) redA[w] = mx;
  __syncthreads();
  mx = fmaxf(fmaxf(redA[0], redA[1]), fmaxf(redA[2], redA[3]));
  float e0 = __expf(v.x - mx), e1 = __expf(v.y - mx);
  float e2 = __expf(v.z - mx), e3 = __expf(v.w - mx);
  float s = e0 + e1 + e2 + e3;
  #pragma unroll
  for (int off = 32; off > 0; off >>= 1) s += __shfl_xor(s, off);
  if (l == 0) redB[w] = s;
  __syncthreads();
  s = redB[0] + redB[1] + redB[2] + redB[3];
  float inv = 1.0f / s;
  ushort4 o;
  o.x = f2bf(e0 * inv); o.y = f2bf(e1 * inv);
  o.z = f2bf(e2 * inv); o.w = f2bf(e3 * inv);
  ((ushort4*)out)[t] = o;
}

// ---------- 2) blockdiagT body: outT = ((blockdiag(K))^T @ in)^T ----------
__device__ __forceinline__ void bdT_body(const float* __restrict__ Kb,
                                         const unsigned short* __restrict__ in,
                                         unsigned short* __restrict__ outT, int bid)
{
  const int n = bid >> 2;
  const int c = (bid & 3) * 256 + threadIdx.x;
  __shared__ float Ks[32][33];
  for (int t = threadIdx.x; t < 1024; t += 256)
    Ks[t >> 5][t & 31] = Kb[n * 1024 + t];
  __syncthreads();
  float ri[32];
  #pragma unroll
  for (int i = 0; i < 32; ++i)
    ri[i] = bf2f(in[(size_t)(n * 32 + i) * 1024 + c]);
  unsigned short ov[32];
  #pragma unroll
  for (int o = 0; o < 32; ++o) {
    float acc = 0.f;
    #pragma unroll
    for (int i = 0; i < 32; ++i) acc = fmaf(Ks[i][o], ri[i], acc);
    ov[o] = f2bf(acc);
  }
  u16x8* dst = (u16x8*)(outT + (size_t)c * 1024 + n * 32);
  const u16x8* src = (const u16x8*)ov;
  #pragma unroll
  for (int q = 0; q < 4; ++q) dst[q] = src[q];
}

// dual: blocks 0-127 -> (Ka,ina,outa), 128-255 -> (Kb2,inb,outb)
__global__ __launch_bounds__(256)
void blockdiagT_dual_kernel(const float* Ka, const unsigned short* ina, unsigned short* outa,
                            const float* Kb2, const unsigned short* inb, unsigned short* outb)
{
  const int bid = blockIdx.x;
  const bool sec = bid >= 128;
  bdT_body(sec ? Kb2 : Ka, sec ? inb : ina, sec ? outb : outa, sec ? bid - 128 : bid);
}

// ---------- 3a) 2-barrier GEMM body (compose chain + fallback): C = A @ B^T ----------
// RBD: fuse right-blockdiag into the epilogue: out[c, n*32+i] = sum_o C[c,n*32+o]*KR[n][o][i]
template<int TILE, bool A_FP32, bool OUT_BIAS, bool RBD>
__device__ __forceinline__ void gemm_body(const void* __restrict__ Av,
                                          const unsigned short* __restrict__ B,
                                          void* __restrict__ Cv, const float* __restrict__ bias,
                                          int N, int K, int nprim, int bid,
                                          const float* __restrict__ KR)
{
  constexpr int FR  = TILE / 32;
  constexpr int SIT = TILE / 32;
  __shared__ unsigned short Asm[TILE * 64];
  __shared__ unsigned short Bsm[TILE * 64];
  const int tid = threadIdx.x;
  const int w = tid >> 6, l = tid & 63;
  const int cpx = nprim >> 3;
  const int swz = (bid & 7) * cpx + (bid >> 3);
  const int ntn = N / TILE;
  const int n0 = (swz % ntn) * TILE;
  const int m0 = (swz / ntn) * TILE;
  const int wr = (w >> 1) * (TILE / 2), wc = (w & 1) * (TILE / 2);
  const int lr = l & 15, kg = (l >> 4) << 3;

  f32x4 acc[FR][FR] = {};
  const int KT = K >> 6;
  for (int kt = 0; kt < KT; ++kt) {
    const int k0 = kt << 6;
    if (kt) __syncthreads();
    #pragma unroll
    for (int it = 0; it < SIT; ++it) {
      int li = it * 256 + tid;
      int row = li >> 3, c8 = (li & 7) << 3;
      const unsigned short* g = B + (size_t)(n0 + row) * K + (k0 + c8);
      gload_lds16(g, (char*)Bsm + it * 4096 + w * 1024);
    }
    if (A_FP32) {
      const float* Af = (const float*)Av;
      #pragma unroll
      for (int p = 0; p < SIT; ++p) {
        int row = (tid >> 3) + p * 32;
        int c8 = (tid & 7) << 3;
        const float* g = Af + (size_t)(m0 + row) * K + (k0 + c8);
        float4 v0 = ((const float4*)g)[0];
        float4 v1 = ((const float4*)g)[1];
        u16x8 uv;
        uv[0] = f2bf(v0.x); uv[1] = f2bf(v0.y); uv[2] = f2bf(v0.z); uv[3] = f2bf(v0.w);
        uv[4] = f2bf(v1.x); uv[5] = f2bf(v1.y); uv[6] = f2bf(v1.z); uv[7] = f2bf(v1.w);
        *(u16x8*)&Asm[row * 64 + c8] = uv;
      }
    } else {
      const unsigned short* Ab = (const unsigned short*)Av;
      #pragma unroll
      for (int it = 0; it < SIT; ++it) {
        int li = it * 256 + tid;
        int row = li >> 3, c8 = (li & 7) << 3;
        const unsigned short* g = Ab + (size_t)(m0 + row) * K + (k0 + c8);
        gload_lds16(g, (char*)Asm + it * 4096 + w * 1024);
      }
    }
    __syncthreads();
    #pragma unroll
    for (int ks = 0; ks < 2; ++ks) {
      const int kb = ks * 32 + kg;
      bf16x8 af[FR], bfr[FR];
      #pragma unroll
      for (int i = 0; i < FR; ++i)
        af[i] = *(const bf16x8*)&Asm[(wr + i * 16 + lr) * 64 + kb];
      #pragma unroll
      for (int j = 0; j < FR; ++j)
        bfr[j] = *(const bf16x8*)&Bsm[(wc + j * 16 + lr) * 64 + kb];
      #pragma unroll
      for (int i = 0; i < FR; ++i)
        #pragma unroll
        for (int j = 0; j < FR; ++j)
          acc[i][j] = __builtin_amdgcn_mfma_f32_16x16x32_bf16(af[i], bfr[j], acc[i][j], 0, 0, 0);
    }
  }
  const int cr = (l >> 4) << 2;
  const int cc = l & 15;
  if (RBD) {
    // fused right-blockdiag epilogue (TILE==64 only): transform 64 cols = 2 K-blocks
    __shared__ float tileS[64][65];
    __shared__ float Kt[2][32][33];
    __syncthreads();
    #pragma unroll
    for (int j = 0; j < FR; ++j)
      #pragma unroll
      for (int i = 0; i < FR; ++i)
        #pragma unroll
        for (int r = 0; r < 4; ++r)
          tileS[wr + i * 16 + cr + r][wc + j * 16 + cc] = acc[i][j][r];
    for (int idx = tid; idx < 2048; idx += 256) {
      int blk = idx >> 10, rem = idx & 1023;
      Kt[blk][rem >> 5][rem & 31] = KR[(size_t)((n0 >> 5) + blk) * 1024 + rem];
    }
    __syncthreads();
    const int row = tid & 63, cq = (tid >> 6) << 4;   // cols cq..cq+15, one 32-block
    const int nb2 = cq >> 5, co = cq & 31;
    float av[16] = {};
    #pragma unroll 4
    for (int o = 0; o < 32; ++o) {
      float a = tileS[row][nb2 * 32 + o];
      #pragma unroll
      for (int ii = 0; ii < 16; ++ii)
        av[ii] = fmaf(a, Kt[nb2][o][co + ii], av[ii]);
    }
    u16x8 ov[2];
    #pragma unroll
    for (int ii = 0; ii < 16; ++ii) ov[ii >> 3][ii & 7] = f2bf(av[ii]);
    unsigned short* Cz = (unsigned short*)Cv;
    u16x8* dst = (u16x8*)&Cz[(size_t)(m0 + row) * N + n0 + cq];
    dst[0] = ov[0]; dst[1] = ov[1];
  } else if (OUT_BIAS) {
    float* C = (float*)Cv;
    #pragma unroll
    for (int j = 0; j < FR; ++j) {
      int col = n0 + wc + j * 16 + cc;
      float bv = bias[col];
      #pragma unroll
      for (int i = 0; i < FR; ++i) {
        int rbase = m0 + wr + i * 16 + cr;
        #pragma unroll
        for (int r = 0; r < 4; ++r)
          C[(size_t)(rbase + r) * N + col] = acc[i][j][r] + bv;
      }
    }
  } else {
    unsigned short* C = (unsigned short*)Cv;
    #pragma unroll
    for (int j = 0; j < FR; ++j) {
      int col = n0 + wc + j * 16 + cc;
      #pragma unroll
      for (int i = 0; i < FR; ++i) {
        int rbase = m0 + wr + i * 16 + cr;
        #pragma unroll
        for (int r = 0; r < 4; ++r)
          C[(size_t)(rbase + r) * N + col] = f2bf(acc[i][j][r]);
      }
    }
  }
}

template<int TILE, bool A_FP32, bool OUT_BIAS>
__global__ __launch_bounds__(256)
void gemm_bt_kernel(const void* __restrict__ Av, const unsigned short* __restrict__ B,
                    void* __restrict__ Cv, const float* __restrict__ bias,
                    int N, int K, int nprim)
{
  gemm_body<TILE, A_FP32, OUT_BIAS, false>(Av, B, Cv, bias, N, K, nprim, blockIdx.x, nullptr);
}

// dual independent 1024^3 bf16 GEMMs: blocks 0-255 -> (A0,B0,C0) plain,
// 256-511 -> (A1,B1,C1) with fused right-blockdiag(KR) epilogue
__global__ __launch_bounds__(256)
void gemm_dual_kernel(const unsigned short* A0, const unsigned short* B0, unsigned short* C0,
                      const unsigned short* A1, const unsigned short* B1, unsigned short* C1,
                      const float* KR)
{
  const int bid = blockIdx.x;
  if (bid < 256)
    gemm_body<64, false, false, false>(A0, B0, (void*)C0, nullptr, 1024, 1024, 256, bid, nullptr);
  else
    gemm_body<64, false, false, true>(A1, B1, (void*)C1, nullptr, 1024, 1024, 256, bid - 256, KR);
}

// ---------- 3b) 256x256 1-barrier-per-tile GEMM (final): C = A(fp32) @ B^T + bias ----------
// Round-10 schedule (best measured, = catalog's minimum-2-phase recipe) with A read
// DIRECTLY as fp32 from x (no Xb convert pass): T14 issue-early/write-late staging —
// fp32 loads issued at tile top, cvt + swizzled ds_write AFTER the MFMA region, published
// by the lgkmcnt(0)+barrier at the next tile top (rule #21: swizzle write & read same XOR).
// B (the composed M matrix, 2 MB, L2-resident) stays on the gload_lds path.
__global__ __launch_bounds__(512, 2)
void gemm256_kernel(const float* __restrict__ A,             // [M,K] fp32 (x)
                    const unsigned short* __restrict__ B,    // [N,K] bf16 (M)
                    float* __restrict__ C, const float* __restrict__ bias,
                    int N, int K)
{
  extern __shared__ __align__(16) char lds[];   // 131072 B
  const int tid = threadIdx.x;
  const int w = tid >> 6, l = tid & 63;
  const int wm = w >> 2, wn = w & 3;
  const int lr = l & 15;
  const int klo = (l >> 4) << 4;      // byte col of k-slot
  const int sw  = (lr & 7) << 4;      // read-side XOR swizzle

  const int nwg = gridDim.x;
  const int bid = blockIdx.x;
  const int cpx = nwg >> 3;
  const int swz = (bid & 7) * cpx + (bid >> 3);
  const int ntn = N >> 8;
  const int n0 = (swz % ntn) << 8;
  const int m0 = (swz / ntn) << 8;

  // B staging source offsets (elements), inverse-swizzled global col
  unsigned int boff[2][2];
  #pragma unroll
  for (int q = 0; q < 2; ++q)
    #pragma unroll
    for (int it = 0; it < 2; ++it) {
      int L = it * 8192 + tid * 16;            // byte pos within half-tile
      int r = L >> 7;                          // row 0..127
      int cs = (L & 127) ^ ((r & 7) << 4);     // source col bytes (pre-swizzled)
      boff[q][it] = (unsigned)(n0 + q * 128 + r) * K + (cs >> 1);
    }
  // A fp32 staging: thread covers rows {p*64 + tid>>3}, k-cols (tid&7)*8..+7
  const int arow = tid >> 3;          // 0..63
  const int acol = (tid & 7) << 3;    // k element base
  char* ldsA = lds;
  char* ldsB = lds + 65536;
  const int wdst = w * 1024;

#define STG_B(bufo, q, k0) do { \
    gload_lds16(B + boff[q][0] + (k0), ldsB + (bufo) + (q) * 16384 + wdst); \
    gload_lds16(B + boff[q][1] + (k0), ldsB + (bufo) + (q) * 16384 + 8192 + wdst); } while (0)
#define A_LOAD(k0) do { \
    _Pragma("unroll") for (int p = 0; p < 4; ++p) { \
      const float* g = A + (size_t)(m0 + p * 64 + arow) * K + (k0) + acol; \
      sa0[p] = ((const float4*)g)[0]; sa1[p] = ((const float4*)g)[1]; } } while (0)
#define A_WRITE(bufo) do { \
    _Pragma("unroll") for (int p = 0; p < 4; ++p) { \
      const int row = p * 64 + arow; \
      u16x8 uv; \
      uv[0] = f2bf(sa0[p].x); uv[1] = f2bf(sa0[p].y); uv[2] = f2bf(sa0[p].z); uv[3] = f2bf(sa0[p].w); \
      uv[4] = f2bf(sa1[p].x); uv[5] = f2bf(sa1[p].y); uv[6] = f2bf(sa1[p].z); uv[7] = f2bf(sa1[p].w); \
      *(u16x8*)(ldsA + (bufo) + ((row >> 7) << 14) + ((row & 127) << 7) \
                + (((acol << 1)) ^ ((row & 7) << 4))) = uv; } } while (0)

  f32x4 acc[2][2][4][2] = {};   // [qi][qj][i][j]
  float4 sa0[4], sa1[4];        // staged A fp32 (held across MFMA region)

  // prologue: stage tile 0 into buf 0
  STG_B(0, 0, 0); STG_B(0, 1, 0);
  A_LOAD(0); A_WRITE(0);

  const int NT = K >> 6;
  int curo = 0;
  for (int t = 0; t < NT; ++t) {
    const int nxto = curo ^ 32768;
    const int k1 = (t + 1) << 6;
    // publish tile t: B via vmcnt(own)+barrier, A via lgkmcnt(own writes)+barrier
    asm volatile("s_waitcnt vmcnt(0) lgkmcnt(0)" ::: "memory");
    __builtin_amdgcn_s_barrier();
    const bool st = (t + 1 < NT);
    // issue next-tile loads early (B direct-to-LDS; A fp32 into registers)
    if (st) { STG_B(nxto, 0, k1); STG_B(nxto, 1, k1); A_LOAD(k1); }
    const char* Ab = ldsA + curo;
    const char* Bb = ldsB + curo;
    // all 24 reads for this tile (ks-major = MFMA consumption order)
    bf16x8 fa[2][2][4];   // [ks][qi][i]
    bf16x8 fb[2][2][2];   // [ks][qj][j]
    #pragma unroll
    for (int ks = 0; ks < 2; ++ks) {
      const int cb = (ks * 64 + klo) ^ sw;
      #pragma unroll
      for (int qi = 0; qi < 2; ++qi)
        #pragma unroll
        for (int i = 0; i < 4; ++i)
          fa[ks][qi][i] = *(const bf16x8*)(Ab + qi * 16384 + (wm * 64 + i * 16 + lr) * 128 + cb);
      #pragma unroll
      for (int qj = 0; qj < 2; ++qj)
        #pragma unroll
        for (int j = 0; j < 2; ++j)
          fb[ks][qj][j] = *(const bf16x8*)(Bb + qj * 16384 + (wn * 32 + j * 16 + lr) * 128 + cb);
    }
    __builtin_amdgcn_s_setprio(1);
    #pragma unroll
    for (int ks = 0; ks < 2; ++ks)
      #pragma unroll
      for (int qi = 0; qi < 2; ++qi)
        #pragma unroll
        for (int i = 0; i < 4; ++i)
          #pragma unroll
          for (int qj = 0; qj < 2; ++qj)
            #pragma unroll
            for (int j = 0; j < 2; ++j)
              acc[qi][qj][i][j] = __builtin_amdgcn_mfma_f32_16x16x32_bf16(
                  fa[ks][qi][i], fb[ks][qj][j], acc[qi][qj][i][j], 0, 0, 0);
    __builtin_amdgcn_s_setprio(0);
    // write-late: cvt + swizzled ds_write of next tile's A (waits its fp32 loads)
    if (st) A_WRITE(nxto);
    curo = nxto;
  }

  // epilogue: C/D layout col = lane&15, row = (lane>>4)*4 + reg
  const int cr = (l >> 4) << 2;
  const int cc = l & 15;
  #pragma unroll
  for (int qi = 0; qi < 2; ++qi)
    #pragma unroll
    for (int qj = 0; qj < 2; ++qj)
      #pragma unroll
      for (int j = 0; j < 2; ++j) {
        const int col = n0 + qj * 128 + wn * 32 + j * 16 + cc;
        const float bvv = bias[col];
        #pragma unroll
        for (int i = 0; i < 4; ++i) {
          const int rbase = m0 + qi * 128 + wm * 64 + i * 16 + cr;
          #pragma unroll
          for (int r = 0; r < 4; ++r)
            C[(size_t)(rbase + r) * N + col] = acc[qi][qj][i][j][r] + bvv;
        }
      }
#undef STG_B
#undef A_LOAD
#undef A_WRITE
}

// ---------- launch ----------
// Tree compose: M = (S3·(B2 S2)) · (B1·(S1·(B0 S0)))
//   bd-dual:  T2=(B2 S2)^T -> t0 ; T0=(B0 S0)^T -> t1
//   gemm-dual: left = S3 @ T2^T -> s0 ; Zt = rightBD(K1, T0 @ S1^T) -> s2 (fused)
//   G3: M = left @ Zt^T -> t0
//   final: out = x(fp32) @ M^T + bias  (direct fp32 A-staging, no convert pass)
extern "C" void kernel_launch(void* const* d_in, const int* in_sizes, int n_in,
                              void* d_out, int out_size, void* d_ws, size_t ws_size,
                              hipStream_t stream) {
  (void)in_sizes; (void)n_in; (void)out_size;
  const float* x    = (const float*)d_in[0];
  const float* P0   = (const float*)d_in[1];
  const float* P1   = (const float*)d_in[2];
  const float* P2   = (const float*)d_in[3];
  const float* P3   = (const float*)d_in[4];
  const float* K0   = (const float*)d_in[5];
  const float* K1   = (const float*)d_in[6];
  const float* K2   = (const float*)d_in[7];
  const float* bias = (const float*)d_in[8];

  unsigned short* S  = (unsigned short*)d_ws;
  unsigned short* s0 = S;
  unsigned short* s1 = S + (1u << 20);
  unsigned short* s2 = S + (2u << 20);
  unsigned short* s3 = S + (3u << 20);
  unsigned short* t0 = S + (4u << 20);
  unsigned short* t1 = S + (5u << 20);

  // 1) softmax of all P
  softmax4_kernel<<<4096, 256, 0, stream>>>(P0, P1, P2, P3, S);

  // 2) both block-diag transposes: T2=(B2 S2)^T -> t0, T0=(B0 S0)^T -> t1
  blockdiagT_dual_kernel<<<256, 256, 0, stream>>>(K2, s2, t0, K0, s0, t1);

  // 3) two independent 1024^3 GEMMs: left -> s0 ; Zt (fused rightBD) -> s2
  gemm_dual_kernel<<<512, 256, 0, stream>>>(s3, t0, s0, t1, s1, s2, K1);

  // 4) M = left @ Zt^T -> t0
  gemm_bt_kernel<64, false, false><<<256, 256, 0, stream>>>((const void*)s0, s2,
      (void*)t0, nullptr, 1024, 1024, 256);

  // 5) final: out = x @ M^T + bias  (A fp32 direct)
  bool ok256 = false;
  {
    hipError_t e = hipFuncSetAttribute((const void*)gemm256_kernel,
                                       hipFuncAttributeMaxDynamicSharedMemorySize, 131072);
    ok256 = (e == hipSuccess);
  }
  if (ok256) {
    gemm256_kernel<<<512, 512, 131072, stream>>>(x, t0, (float*)d_out, bias, 1024, 1024);
  } else {
    gemm_bt_kernel<128, true, true><<<2048, 256, 0, stream>>>((const void*)x, t0,
        d_out, bias, 1024, 1024, 2048);
  }
}

// Round 12
// 158.323 us; speedup vs baseline: 1.9470x; 1.9470x over previous
//
#include <hip/hip_runtime.h>
#include <hip/hip_bf16.h>

// ---------- helpers ----------
typedef __bf16 bf16x8 __attribute__((ext_vector_type(8)));
typedef float f32x4 __attribute__((ext_vector_type(4)));
typedef unsigned short u16x8 __attribute__((ext_vector_type(8)));

__device__ __forceinline__ unsigned short f2bf(float f) {
  unsigned u = __float_as_uint(f);
  u += 0x7FFF + ((u >> 16) & 1);          // RNE
  return (unsigned short)(u >> 16);
}
__device__ __forceinline__ float bf2f(unsigned short h) {
  return __uint_as_float((unsigned)h << 16);
}

__device__ __forceinline__ void gload_lds16(const void* g, void* l) {
  __builtin_amdgcn_global_load_lds(
      (const __attribute__((address_space(1))) void*)g,
      (__attribute__((address_space(3))) void*)l, 16, 0, 0);
}

// grid-strided fp32->bf16 convert slice, run by tail blocks of latency-bound launches
__device__ __forceinline__ void convert_slice(const float* __restrict__ x,
                                              unsigned short* __restrict__ xb,
                                              int base8, int cnt8, int cb, int nb)
{
  int i = cb * 256 + (int)threadIdx.x;
  const int stride = nb * 256;
  for (; i < cnt8; i += stride) {
    const size_t g = (size_t)(base8 + i);
    float4 v0 = ((const float4*)x)[2 * g];
    float4 v1 = ((const float4*)x)[2 * g + 1];
    u16x8 uv;
    uv[0] = f2bf(v0.x); uv[1] = f2bf(v0.y); uv[2] = f2bf(v0.z); uv[3] = f2bf(v0.w);
    uv[4] = f2bf(v1.x); uv[5] = f2bf(v1.y); uv[6] = f2bf(v1.z); uv[7] = f2bf(v1.w);
    ((u16x8*)xb)[g] = uv;
  }
}

// ---------- 1) row softmax of 4 P matrices -> bf16 (+ convert tail blocks) ----------
__global__ __launch_bounds__(256)
void softmax4_kernel(const float* __restrict__ P0, const float* __restrict__ P1,
                     const float* __restrict__ P2, const float* __restrict__ P3,
                     unsigned short* __restrict__ S,
                     const float* __restrict__ cvx, unsigned short* __restrict__ cvxb,
                     int cvt_cnt)
{
  if (blockIdx.x >= 4096) {
    convert_slice(cvx, cvxb, 0, cvt_cnt, blockIdx.x - 4096, gridDim.x - 4096);
    return;
  }
  const int bid = blockIdx.x;
  const int mat = bid >> 10, row = bid & 1023;
  const float* P = (mat == 0 ? P0 : mat == 1 ? P1 : mat == 2 ? P2 : P3) + (size_t)row * 1024;
  unsigned short* out = S + ((size_t)mat << 20) + (size_t)row * 1024;
  const int t = threadIdx.x, w = t >> 6, l = t & 63;
  float4 v = ((const float4*)P)[t];
  float mx = fmaxf(fmaxf(v.x, v.y), fmaxf(v.z, v.w));
  #pragma unroll
  for (int off = 32; off > 0; off >>= 1) mx = fmaxf(mx, __shfl_xor(mx, off));
  __shared__ float redA[4], redB[4];
  if (l == 0) redA[w] = mx;
  __syncthreads();
  mx = fmaxf(fmaxf(redA[0], redA[1]), fmaxf(redA[2], redA[3]));
  float e0 = __expf(v.x - mx), e1 = __expf(v.y - mx);
  float e2 = __expf(v.z - mx), e3 = __expf(v.w - mx);
  float s = e0 + e1 + e2 + e3;
  #pragma unroll
  for (int off = 32; off > 0; off >>= 1) s += __shfl_xor(s, off);
  if (l == 0) redB[w] = s;
  __syncthreads();
  s = redB[0] + redB[1] + redB[2] + redB[3];
  float inv = 1.0f / s;
  ushort4 o;
  o.x = f2bf(e0 * inv); o.y = f2bf(e1 * inv);
  o.z = f2bf(e2 * inv); o.w = f2bf(e3 * inv);
  ((ushort4*)out)[t] = o;
}

// ---------- 2) blockdiagT body: outT = ((blockdiag(K))^T @ in)^T ----------
__device__ __forceinline__ void bdT_body(const float* __restrict__ Kb,
                                         const unsigned short* __restrict__ in,
                                         unsigned short* __restrict__ outT, int bid)
{
  const int n = bid >> 2;
  const int c = (bid & 3) * 256 + threadIdx.x;
  __shared__ float Ks[32][33];
  for (int t = threadIdx.x; t < 1024; t += 256)
    Ks[t >> 5][t & 31] = Kb[n * 1024 + t];
  __syncthreads();
  float ri[32];
  #pragma unroll
  for (int i = 0; i < 32; ++i)
    ri[i] = bf2f(in[(size_t)(n * 32 + i) * 1024 + c]);
  unsigned short ov[32];
  #pragma unroll
  for (int o = 0; o < 32; ++o) {
    float acc = 0.f;
    #pragma unroll
    for (int i = 0; i < 32; ++i) acc = fmaf(Ks[i][o], ri[i], acc);
    ov[o] = f2bf(acc);
  }
  u16x8* dst = (u16x8*)(outT + (size_t)c * 1024 + n * 32);
  const u16x8* src = (const u16x8*)ov;
  #pragma unroll
  for (int q = 0; q < 4; ++q) dst[q] = src[q];
}

// dual: blocks 0-127 -> (Ka,ina,outa), 128-255 -> (Kb2,inb,outb), >=256 convert
__global__ __launch_bounds__(256)
void blockdiagT_dual_kernel(const float* Ka, const unsigned short* ina, unsigned short* outa,
                            const float* Kb2, const unsigned short* inb, unsigned short* outb,
                            const float* cvx, unsigned short* cvxb, int cvt_base, int cvt_cnt)
{
  const int bid = blockIdx.x;
  if (bid >= 256) {
    convert_slice(cvx, cvxb, cvt_base, cvt_cnt, bid - 256, gridDim.x - 256);
    return;
  }
  const bool sec = bid >= 128;
  bdT_body(sec ? Kb2 : Ka, sec ? inb : ina, sec ? outb : outa, sec ? bid - 128 : bid);
}

// ---------- 3a) 2-barrier GEMM body (compose chain + fallback): C = A @ B^T ----------
// RBD: fuse right-blockdiag into the epilogue: out[c, n*32+i] = sum_o C[c,n*32+o]*KR[n][o][i]
template<int TILE, bool A_FP32, bool OUT_BIAS, bool RBD>
__device__ __forceinline__ void gemm_body(const void* __restrict__ Av,
                                          const unsigned short* __restrict__ B,
                                          void* __restrict__ Cv, const float* __restrict__ bias,
                                          int N, int K, int nprim, int bid,
                                          const float* __restrict__ KR)
{
  constexpr int FR  = TILE / 32;
  constexpr int SIT = TILE / 32;
  __shared__ unsigned short Asm[TILE * 64];
  __shared__ unsigned short Bsm[TILE * 64];
  const int tid = threadIdx.x;
  const int w = tid >> 6, l = tid & 63;
  const int cpx = nprim >> 3;
  const int swz = (bid & 7) * cpx + (bid >> 3);
  const int ntn = N / TILE;
  const int n0 = (swz % ntn) * TILE;
  const int m0 = (swz / ntn) * TILE;
  const int wr = (w >> 1) * (TILE / 2), wc = (w & 1) * (TILE / 2);
  const int lr = l & 15, kg = (l >> 4) << 3;

  f32x4 acc[FR][FR] = {};
  const int KT = K >> 6;
  for (int kt = 0; kt < KT; ++kt) {
    const int k0 = kt << 6;
    if (kt) __syncthreads();
    #pragma unroll
    for (int it = 0; it < SIT; ++it) {
      int li = it * 256 + tid;
      int row = li >> 3, c8 = (li & 7) << 3;
      const unsigned short* g = B + (size_t)(n0 + row) * K + (k0 + c8);
      gload_lds16(g, (char*)Bsm + it * 4096 + w * 1024);
    }
    if (A_FP32) {
      const float* Af = (const float*)Av;
      #pragma unroll
      for (int p = 0; p < SIT; ++p) {
        int row = (tid >> 3) + p * 32;
        int c8 = (tid & 7) << 3;
        const float* g = Af + (size_t)(m0 + row) * K + (k0 + c8);
        float4 v0 = ((const float4*)g)[0];
        float4 v1 = ((const float4*)g)[1];
        u16x8 uv;
        uv[0] = f2bf(v0.x); uv[1] = f2bf(v0.y); uv[2] = f2bf(v0.z); uv[3] = f2bf(v0.w);
        uv[4] = f2bf(v1.x); uv[5] = f2bf(v1.y); uv[6] = f2bf(v1.z); uv[7] = f2bf(v1.w);
        *(u16x8*)&Asm[row * 64 + c8] = uv;
      }
    } else {
      const unsigned short* Ab = (const unsigned short*)Av;
      #pragma unroll
      for (int it = 0; it < SIT; ++it) {
        int li = it * 256 + tid;
        int row = li >> 3, c8 = (li & 7) << 3;
        const unsigned short* g = Ab + (size_t)(m0 + row) * K + (k0 + c8);
        gload_lds16(g, (char*)Asm + it * 4096 + w * 1024);
      }
    }
    __syncthreads();
    #pragma unroll
    for (int ks = 0; ks < 2; ++ks) {
      const int kb = ks * 32 + kg;
      bf16x8 af[FR], bfr[FR];
      #pragma unroll
      for (int i = 0; i < FR; ++i)
        af[i] = *(const bf16x8*)&Asm[(wr + i * 16 + lr) * 64 + kb];
      #pragma unroll
      for (int j = 0; j < FR; ++j)
        bfr[j] = *(const bf16x8*)&Bsm[(wc + j * 16 + lr) * 64 + kb];
      #pragma unroll
      for (int i = 0; i < FR; ++i)
        #pragma unroll
        for (int j = 0; j < FR; ++j)
          acc[i][j] = __builtin_amdgcn_mfma_f32_16x16x32_bf16(af[i], bfr[j], acc[i][j], 0, 0, 0);
    }
  }
  const int cr = (l >> 4) << 2;
  const int cc = l & 15;
  if (RBD) {
    // fused right-blockdiag epilogue (TILE==64 only): transform 64 cols = 2 K-blocks
    __shared__ float tileS[64][65];
    __shared__ float Kt[2][32][33];
    __syncthreads();
    #pragma unroll
    for (int j = 0; j < FR; ++j)
      #pragma unroll
      for (int i = 0; i < FR; ++i)
        #pragma unroll
        for (int r = 0; r < 4; ++r)
          tileS[wr + i * 16 + cr + r][wc + j * 16 + cc] = acc[i][j][r];
    for (int idx = tid; idx < 2048; idx += 256) {
      int blk = idx >> 10, rem = idx & 1023;
      Kt[blk][rem >> 5][rem & 31] = KR[(size_t)((n0 >> 5) + blk) * 1024 + rem];
    }
    __syncthreads();
    const int row = tid & 63, cq = (tid >> 6) << 4;   // cols cq..cq+15, one 32-block
    const int nb2 = cq >> 5, co = cq & 31;
    float av[16] = {};
    #pragma unroll 4
    for (int o = 0; o < 32; ++o) {
      float a = tileS[row][nb2 * 32 + o];
      #pragma unroll
      for (int ii = 0; ii < 16; ++ii)
        av[ii] = fmaf(a, Kt[nb2][o][co + ii], av[ii]);
    }
    u16x8 ov[2];
    #pragma unroll
    for (int ii = 0; ii < 16; ++ii) ov[ii >> 3][ii & 7] = f2bf(av[ii]);
    unsigned short* Cz = (unsigned short*)Cv;
    u16x8* dst = (u16x8*)&Cz[(size_t)(m0 + row) * N + n0 + cq];
    dst[0] = ov[0]; dst[1] = ov[1];
  } else if (OUT_BIAS) {
    float* C = (float*)Cv;
    #pragma unroll
    for (int j = 0; j < FR; ++j) {
      int col = n0 + wc + j * 16 + cc;
      float bv = bias[col];
      #pragma unroll
      for (int i = 0; i < FR; ++i) {
        int rbase = m0 + wr + i * 16 + cr;
        #pragma unroll
        for (int r = 0; r < 4; ++r)
          C[(size_t)(rbase + r) * N + col] = acc[i][j][r] + bv;
      }
    }
  } else {
    unsigned short* C = (unsigned short*)Cv;
    #pragma unroll
    for (int j = 0; j < FR; ++j) {
      int col = n0 + wc + j * 16 + cc;
      #pragma unroll
      for (int i = 0; i < FR; ++i) {
        int rbase = m0 + wr + i * 16 + cr;
        #pragma unroll
        for (int r = 0; r < 4; ++r)
          C[(size_t)(rbase + r) * N + col] = f2bf(acc[i][j][r]);
      }
    }
  }
}

template<int TILE, bool A_FP32, bool OUT_BIAS>
__global__ __launch_bounds__(256)
void gemm_bt_kernel(const void* __restrict__ Av, const unsigned short* __restrict__ B,
                    void* __restrict__ Cv, const float* __restrict__ bias,
                    int N, int K, int nprim,
                    const float* cvx, unsigned short* cvxb, int cvt_base, int cvt_cnt)
{
  if ((int)blockIdx.x >= nprim) {
    convert_slice(cvx, cvxb, cvt_base, cvt_cnt, blockIdx.x - nprim, gridDim.x - nprim);
    return;
  }
  gemm_body<TILE, A_FP32, OUT_BIAS, false>(Av, B, Cv, bias, N, K, nprim, blockIdx.x, nullptr);
}

// dual independent 1024^3 bf16 GEMMs: blocks 0-255 -> (A0,B0,C0) plain,
// 256-511 -> (A1,B1,C1) with fused right-blockdiag(KR) epilogue, >=512 convert
__global__ __launch_bounds__(256)
void gemm_dual_kernel(const unsigned short* A0, const unsigned short* B0, unsigned short* C0,
                      const unsigned short* A1, const unsigned short* B1, unsigned short* C1,
                      const float* KR,
                      const float* cvx, unsigned short* cvxb, int cvt_base, int cvt_cnt)
{
  const int bid = blockIdx.x;
  if (bid >= 512) {
    convert_slice(cvx, cvxb, cvt_base, cvt_cnt, bid - 512, gridDim.x - 512);
    return;
  }
  if (bid < 256)
    gemm_body<64, false, false, false>(A0, B0, (void*)C0, nullptr, 1024, 1024, 256, bid, nullptr);
  else
    gemm_body<64, false, false, true>(A1, B1, (void*)C1, nullptr, 1024, 1024, 256, bid - 256, KR);
}

// ---------- 3b) 256x256 1-barrier-per-tile GEMM (final): C = A @ B^T + bias ----------
// ROUND-10 VERBATIM (best measured: 84.3 us, MfmaUtil 33%, 0 bank conflicts).
// Per K-tile: {per-wave vmcnt(0) -> barrier -> stage t+1 into other buffer ->
// 24 ds_read_b128 -> 32 MFMA under setprio}. Single sync point per tile.
__global__ __launch_bounds__(512, 2)
void gemm256_kernel(const unsigned short* __restrict__ A,   // [M,K] bf16
                    const unsigned short* __restrict__ B,   // [N,K] bf16
                    float* __restrict__ C, const float* __restrict__ bias,
                    int N, int K)
{
  extern __shared__ __align__(16) char lds[];   // 131072 B
  const int tid = threadIdx.x;
  const int w = tid >> 6, l = tid & 63;
  const int wm = w >> 2, wn = w & 3;
  const int lr = l & 15;
  const int klo = (l >> 4) << 4;      // byte col of k-slot
  const int sw  = (lr & 7) << 4;      // read-side XOR swizzle

  const int nwg = gridDim.x;
  const int bid = blockIdx.x;
  const int cpx = nwg >> 3;
  const int swz = (bid & 7) * cpx + (bid >> 3);
  const int ntn = N >> 8;
  const int n0 = (swz % ntn) << 8;
  const int m0 = (swz / ntn) << 8;

  // staging source offsets (elements), inverse-swizzled global col
  unsigned int aoff[2][2], boff[2][2];
  #pragma unroll
  for (int q = 0; q < 2; ++q)
    #pragma unroll
    for (int it = 0; it < 2; ++it) {
      int L = it * 8192 + tid * 16;            // byte pos within half-tile
      int r = L >> 7;                          // row 0..127
      int cs = (L & 127) ^ ((r & 7) << 4);     // source col bytes (pre-swizzled)
      aoff[q][it] = (unsigned)(m0 + q * 128 + r) * K + (cs >> 1);
      boff[q][it] = (unsigned)(n0 + q * 128 + r) * K + (cs >> 1);
    }
  char* ldsA = lds;
  char* ldsB = lds + 65536;
  const int wdst = w * 1024;

#define STG_A(bufo, q, k0) do { \
    gload_lds16(A + aoff[q][0] + (k0), ldsA + (bufo) + (q) * 16384 + wdst); \
    gload_lds16(A + aoff[q][1] + (k0), ldsA + (bufo) + (q) * 16384 + 8192 + wdst); } while (0)
#define STG_B(bufo, q, k0) do { \
    gload_lds16(B + boff[q][0] + (k0), ldsB + (bufo) + (q) * 16384 + wdst); \
    gload_lds16(B + boff[q][1] + (k0), ldsB + (bufo) + (q) * 16384 + 8192 + wdst); } while (0)

  f32x4 acc[2][2][4][2] = {};   // [qi][qj][i][j]

  // prologue: stage tile 0 into buf 0
  STG_A(0, 0, 0); STG_B(0, 0, 0); STG_B(0, 1, 0); STG_A(0, 1, 0);

  const int NT = K >> 6;
  int curo = 0;
  for (int t = 0; t < NT; ++t) {
    const int nxto = curo ^ 32768;
    const int k1 = (t + 1) << 6;
    // publish tile t: per-wave drain of own staged slice, then block-wide barrier
    asm volatile("s_waitcnt vmcnt(0)" ::: "memory");
    __builtin_amdgcn_s_barrier();
    // stage tile t+1 first (earliest issue -> max lag for next drain)
    if (t + 1 < NT) { STG_A(nxto, 0, k1); STG_B(nxto, 0, k1); STG_B(nxto, 1, k1); STG_A(nxto, 1, k1); }
    const char* Ab = ldsA + curo;
    const char* Bb = ldsB + curo;
    // all 24 reads for this tile (ks-major = MFMA consumption order)
    bf16x8 av[2][2][4];   // [ks][qi][i]
    bf16x8 bvr[2][2][2];  // [ks][qj][j]
    #pragma unroll
    for (int ks = 0; ks < 2; ++ks) {
      const int cb = (ks * 64 + klo) ^ sw;
      #pragma unroll
      for (int qi = 0; qi < 2; ++qi)
        #pragma unroll
        for (int i = 0; i < 4; ++i)
          av[ks][qi][i] = *(const bf16x8*)(Ab + qi * 16384 + (wm * 64 + i * 16 + lr) * 128 + cb);
      #pragma unroll
      for (int qj = 0; qj < 2; ++qj)
        #pragma unroll
        for (int j = 0; j < 2; ++j)
          bvr[ks][qj][j] = *(const bf16x8*)(Bb + qj * 16384 + (wn * 32 + j * 16 + lr) * 128 + cb);
    }
    __builtin_amdgcn_s_setprio(1);
    #pragma unroll
    for (int ks = 0; ks < 2; ++ks)
      #pragma unroll
      for (int qi = 0; qi < 2; ++qi)
        #pragma unroll
        for (int i = 0; i < 4; ++i)
          #pragma unroll
          for (int qj = 0; qj < 2; ++qj)
            #pragma unroll
            for (int j = 0; j < 2; ++j)
              acc[qi][qj][i][j] = __builtin_amdgcn_mfma_f32_16x16x32_bf16(
                  av[ks][qi][i], bvr[ks][qj][j], acc[qi][qj][i][j], 0, 0, 0);
    __builtin_amdgcn_s_setprio(0);
    curo = nxto;
  }

  // epilogue: C/D layout col = lane&15, row = (lane>>4)*4 + reg
  const int cr = (l >> 4) << 2;
  const int cc = l & 15;
  #pragma unroll
  for (int qi = 0; qi < 2; ++qi)
    #pragma unroll
    for (int qj = 0; qj < 2; ++qj)
      #pragma unroll
      for (int j = 0; j < 2; ++j) {
        const int col = n0 + qj * 128 + wn * 32 + j * 16 + cc;
        const float bvv = bias[col];
        #pragma unroll
        for (int i = 0; i < 4; ++i) {
          const int rbase = m0 + qi * 128 + wm * 64 + i * 16 + cr;
          #pragma unroll
          for (int r = 0; r < 4; ++r)
            C[(size_t)(rbase + r) * N + col] = acc[qi][qj][i][j][r] + bvv;
        }
      }
#undef STG_A
#undef STG_B
}

// ---------- launch ----------
// Tree compose: M = (S3·(B2 S2)) · (B1·(S1·(B0 S0)))
//   bd-dual:  T2=(B2 S2)^T -> t0 ; T0=(B0 S0)^T -> t1
//   gemm-dual: left = S3 @ T2^T -> s0 ; Zt = rightBD(K1, T0 @ S1^T) -> s2 (fused, NOT in-place)
//   G3: M = left @ Zt^T -> t0
//   final: out = Xb @ M^T + bias
extern "C" void kernel_launch(void* const* d_in, const int* in_sizes, int n_in,
                              void* d_out, int out_size, void* d_ws, size_t ws_size,
                              hipStream_t stream) {
  (void)in_sizes; (void)n_in; (void)out_size;
  const float* x    = (const float*)d_in[0];
  const float* P0   = (const float*)d_in[1];
  const float* P1   = (const float*)d_in[2];
  const float* P2   = (const float*)d_in[3];
  const float* P3   = (const float*)d_in[4];
  const float* K0   = (const float*)d_in[5];
  const float* K1   = (const float*)d_in[6];
  const float* K2   = (const float*)d_in[7];
  const float* bias = (const float*)d_in[8];

  unsigned short* S  = (unsigned short*)d_ws;
  unsigned short* s0 = S;
  unsigned short* s1 = S + (1u << 20);
  unsigned short* s2 = S + (2u << 20);
  unsigned short* s3 = S + (3u << 20);
  unsigned short* t0 = S + (4u << 20);
  unsigned short* t1 = S + (5u << 20);
  unsigned short* Xb = S + (6u << 20);
  const size_t need = ((size_t)6 * (1u << 20) + (size_t)32768 * 1024) * 2;
  const bool have_xb = ws_size >= need;
  unsigned short* xbp = have_xb ? Xb : nullptr;

  // convert distributed in 8 slices of 512K ushort8-groups across 4 chain launches
  const int SL = 524288;
  const int cvt2 = have_xb ? 2 * SL : 0;
  const int tail_smx = have_xb ? 1024 : 0;
  const int tail_512 = have_xb ? 512 : 0;

  // 1) softmax of all P (+2 cvt slices)
  softmax4_kernel<<<4096 + tail_smx, 256, 0, stream>>>(P0, P1, P2, P3, S, x, xbp, cvt2);

  // 2) both block-diag transposes (+2 slices): T2=(B2 S2)^T -> t0, T0=(B0 S0)^T -> t1
  blockdiagT_dual_kernel<<<256 + tail_512, 256, 0, stream>>>(K2, s2, t0, K0, s0, t1,
                                                             x, xbp, 2 * SL, cvt2);

  // 3) two independent 1024^3 GEMMs (+2 slices): left -> s0 ; Zt (fused rightBD) -> s2
  gemm_dual_kernel<<<512 + tail_512, 256, 0, stream>>>(s3, t0, s0, t1, s1, s2, K1,
                                                       x, xbp, 4 * SL, cvt2);

  // 4) M = left @ Zt^T -> t0  (+2 slices)
  gemm_bt_kernel<64, false, false><<<256 + tail_512, 256, 0, stream>>>((const void*)s0, s2,
      (void*)t0, nullptr, 1024, 1024, 256, x, xbp, 6 * SL, cvt2);

  // 5) final: out = Xb @ M^T + bias
  bool ok256 = false;
  if (have_xb) {
    hipError_t e = hipFuncSetAttribute((const void*)gemm256_kernel,
                                       hipFuncAttributeMaxDynamicSharedMemorySize, 131072);
    ok256 = (e == hipSuccess);
  }
  if (ok256) {
    gemm256_kernel<<<512, 512, 131072, stream>>>(Xb, t0, (float*)d_out, bias, 1024, 1024);
  } else if (have_xb) {
    gemm_bt_kernel<128, false, true><<<2048, 256, 0, stream>>>((const void*)Xb, t0,
        d_out, bias, 1024, 1024, 2048, nullptr, nullptr, 0, 0);
  } else {
    gemm_bt_kernel<128, true, true><<<2048, 256, 0, stream>>>((const void*)x, t0,
        d_out, bias, 1024, 1024, 2048, nullptr, nullptr, 0, 0);
  }
}